// Round 6
// baseline (205.577 us; speedup 1.0000x reference)
//
#include <hip/hip_runtime.h>
#include <float.h>
#include <stdint.h>

#define B_  2
#define S_  2048
#define N_  1024
#define H_  1024
#define NH_ 16
#define K_  1024

typedef __attribute__((ext_vector_type(8))) short bf16x8;
typedef __attribute__((ext_vector_type(4))) float f32x4;

typedef __attribute__((address_space(3))) uint32_t lds_u32;
typedef __attribute__((address_space(1))) uint32_t glb_u32;

// async global->LDS, 16B per lane; LDS dest = wave-uniform base + lane*16
__device__ __forceinline__ void gload16(void* l, const void* g) {
    __builtin_amdgcn_global_load_lds((const glb_u32*)g, (lds_u32*)l, 16, 0, 0);
}

// round-to-nearest-even fp32 -> bf16 bits
__device__ __forceinline__ ushort f2bf(float f) {
    uint32_t u = __float_as_uint(f);
    u = (u + 0x7fffu + ((u >> 16) & 1u)) >> 16;
    return (ushort)u;
}

#if __has_builtin(__builtin_amdgcn_cvt_pk_bf16_f32)
typedef __attribute__((ext_vector_type(2))) __bf16 bfp2;
__device__ __forceinline__ uint pk2(float a, float b) {
    bfp2 v = __builtin_amdgcn_cvt_pk_bf16_f32(a, b);
    return __builtin_bit_cast(uint, v);
}
#else
__device__ __forceinline__ uint pk2(float a, float b) {
    return (uint)f2bf(a) | ((uint)f2bf(b) << 16);
}
#endif

__device__ __forceinline__ float fexp2(float x) {
#if __has_builtin(__builtin_amdgcn_exp2f)
    return __builtin_amdgcn_exp2f(x);
#else
    return exp2f(x);
#endif
}

#define SC2 0.180336880f   /* (1/sqrt(64)) * log2(e) — folded into Q proj */

// ---------------------------------------------------------------------------
// Unified 128x128-tile bf16 MFMA GEMM, fp32 sources converted in staging,
// register-double-buffered K-loop (loads for kt+1 issue before compute of kt,
// so global latency hides under MFMA across the barrier).
// mode 0 (512 WGs): idx<256 -> Qp = tq@Wq^T * SC2 (bf16); idx<384 -> Kp =
//   kv@Wk^T (bf16); else -> VtG = transpose-per-head(kv@Wv^T) + VmP partial
//   column sums (race-free, one slot per (m-tile, col)).
// mode 1 (256 WGs): out = AO@Wo^T (fp32), AO staged as bf16 passthrough.
// ---------------------------------------------------------------------------
__global__ __launch_bounds__(512) void gemm_all(int mode,
        const float* __restrict__ tqF, const float* __restrict__ kvF,
        const float* __restrict__ wqF, const float* __restrict__ wkF,
        const float* __restrict__ wvF, const float* __restrict__ woF,
        ushort* __restrict__ Qp, ushort* __restrict__ Kp,
        ushort* __restrict__ VtG, const ushort* __restrict__ AO,
        float* __restrict__ outF, float* __restrict__ VmP)
{
    __shared__ __align__(16) ushort smem[17408];   // Xs | Ws ; reused as T in kind-2
    ushort* Xs = smem;
    ushort* Ws = smem + 8192;

    const float* XF = nullptr; const float* WF; void* Yp; int kind; float scale = 1.f;
    int bm, bn;
    if (mode == 1) {
        WF = woF; Yp = outF; kind = 1;
        bm = (blockIdx.x >> 3) * 128; bn = (blockIdx.x & 7) * 128;
    } else {
        int idx = blockIdx.x;
        if (idx < 256)      { XF = tqF; WF = wqF; Yp = Qp;  kind = 0; scale = SC2;
                              bm = (idx >> 3) * 128; bn = (idx & 7) * 128; }
        else if (idx < 384) { int j = idx - 256; XF = kvF; WF = wkF; Yp = Kp; kind = 0;
                              bm = (j >> 3) * 128; bn = (j & 7) * 128; }
        else                { int j = idx - 384; XF = kvF; WF = wvF; Yp = VtG; kind = 2;
                              bm = (j >> 3) * 128; bn = (j & 7) * 128; }
    }

    const int tid = threadIdx.x;
    const int lane = tid & 63, w = tid >> 6;
    const int wy = w >> 1, wx = w & 1;
    const int c = lane & 15, g = lane >> 4;

    // staging map: this lane owns 16B LDS units u0,u1 of Xs and Ws
    const int u0 = w * 128 + lane,      row0 = u0 >> 3, gs0 = (u0 & 7) ^ (row0 & 7);
    const int u1 = w * 128 + 64 + lane, row1 = u1 >> 3, gs1 = (u1 & 7) ^ (row1 & 7);

    const ushort* xb0 = nullptr; const ushort* xb1 = nullptr;
    const float *xs0 = nullptr, *xs1 = nullptr;
    if (mode == 1) {
        xb0 = AO + (size_t)(bm + row0) * K_ + gs0 * 8;
        xb1 = AO + (size_t)(bm + row1) * K_ + gs1 * 8;
    } else {
        xs0 = XF + (size_t)(bm + row0) * K_ + gs0 * 8;
        xs1 = XF + (size_t)(bm + row1) * K_ + gs1 * 8;
    }
    const float* ws0 = WF + (size_t)(bn + row0) * K_ + gs0 * 8;
    const float* ws1 = WF + (size_t)(bn + row1) * K_ + gs1 * 8;

    float4 x0a, x0b, x1a, x1b, w0a, w0b, w1a, w1b;
    uint4 bx0, bx1;

    auto loadX = [&](int k0) {
        if (mode == 1) {
            bx0 = *(const uint4*)(xb0 + k0);
            bx1 = *(const uint4*)(xb1 + k0);
        } else {
            x0a = *(const float4*)(xs0 + k0); x0b = *(const float4*)(xs0 + k0 + 4);
            x1a = *(const float4*)(xs1 + k0); x1b = *(const float4*)(xs1 + k0 + 4);
        }
        w0a = *(const float4*)(ws0 + k0); w0b = *(const float4*)(ws0 + k0 + 4);
        w1a = *(const float4*)(ws1 + k0); w1b = *(const float4*)(ws1 + k0 + 4);
    };

    f32x4 acc[2][4] = {};

    loadX(0);
    for (int kt = 0; kt < 16; ++kt) {
        __syncthreads();   // previous iteration's LDS consumers done
        if (mode == 1) {
            *(uint4*)(Xs + u0 * 8) = bx0;
            *(uint4*)(Xs + u1 * 8) = bx1;
        } else {
            uint4 t0v = make_uint4(pk2(x0a.x, x0a.y), pk2(x0a.z, x0a.w),
                                   pk2(x0b.x, x0b.y), pk2(x0b.z, x0b.w));
            uint4 t1v = make_uint4(pk2(x1a.x, x1a.y), pk2(x1a.z, x1a.w),
                                   pk2(x1b.x, x1b.y), pk2(x1b.z, x1b.w));
            *(uint4*)(Xs + u0 * 8) = t0v;
            *(uint4*)(Xs + u1 * 8) = t1v;
        }
        {
            uint4 s0 = make_uint4(pk2(w0a.x, w0a.y), pk2(w0a.z, w0a.w),
                                  pk2(w0b.x, w0b.y), pk2(w0b.z, w0b.w));
            uint4 s1 = make_uint4(pk2(w1a.x, w1a.y), pk2(w1a.z, w1a.w),
                                  pk2(w1b.x, w1b.y), pk2(w1b.z, w1b.w));
            *(uint4*)(Ws + u0 * 8) = s0;
            *(uint4*)(Ws + u1 * 8) = s1;
        }
        __syncthreads();
        if (kt < 15) loadX((kt + 1) * 64);   // prefetch next tile into regs

#pragma unroll
        for (int ks = 0; ks < 2; ++ks) {
            bf16x8 af[2], bfr[4];
#pragma unroll
            for (int mi = 0; mi < 2; ++mi) {
                int row = wy * 32 + mi * 16 + c;
                int s = ks * 4 + g;
                af[mi] = *(const bf16x8*)(Xs + (row * 8 + (s ^ (row & 7))) * 8);
            }
#pragma unroll
            for (int ni = 0; ni < 4; ++ni) {
                int row = wx * 64 + ni * 16 + c;
                int s = ks * 4 + g;
                bfr[ni] = *(const bf16x8*)(Ws + (row * 8 + (s ^ (row & 7))) * 8);
            }
#pragma unroll
            for (int mi = 0; mi < 2; ++mi)
#pragma unroll
                for (int ni = 0; ni < 4; ++ni)
                    acc[mi][ni] = __builtin_amdgcn_mfma_f32_16x16x32_bf16(af[mi], bfr[ni], acc[mi][ni], 0, 0, 0);
        }
    }

    if (kind == 0) {
        ushort* Y = (ushort*)Yp;
#pragma unroll
        for (int mi = 0; mi < 2; ++mi)
#pragma unroll
            for (int ni = 0; ni < 4; ++ni)
#pragma unroll
                for (int r = 0; r < 4; ++r) {
                    int row = bm + wy * 32 + mi * 16 + g * 4 + r;
                    int col = bn + wx * 64 + ni * 16 + c;
                    Y[(size_t)row * 1024 + col] = f2bf(acc[mi][ni][r] * scale);
                }
    } else if (kind == 1) {
        float* Y = (float*)Yp;
#pragma unroll
        for (int mi = 0; mi < 2; ++mi)
#pragma unroll
            for (int ni = 0; ni < 4; ++ni)
#pragma unroll
                for (int r = 0; r < 4; ++r) {
                    int row = bm + wy * 32 + mi * 16 + g * 4 + r;
                    int col = bn + wx * 64 + ni * 16 + c;
                    Y[(size_t)row * 1024 + col] = acc[mi][ni][r];
                }
    } else {
        // V transposed per head + VmP partial column sums
        ushort* T = smem;                       // [128][136]
        __syncthreads();                        // done with Xs/Ws
#pragma unroll
        for (int mi = 0; mi < 2; ++mi)
#pragma unroll
            for (int ni = 0; ni < 4; ++ni) {
                ushort4 v4;
                v4.x = f2bf(acc[mi][ni][0]); v4.y = f2bf(acc[mi][ni][1]);
                v4.z = f2bf(acc[mi][ni][2]); v4.w = f2bf(acc[mi][ni][3]);
                *(ushort4*)&T[(wx * 64 + ni * 16 + c) * 136 + wy * 32 + mi * 16 + g * 4] = v4;
            }
        __syncthreads();
        ushort* Vt = (ushort*)Yp;
        int b = bm >> 10;
        int rid = tid >> 2, quad = tid & 3;
        int n_c = bn + rid;                     // col (h*64+d) in [0,1024)
        int h = n_c >> 6, d = n_c & 63;
        int m0 = quad * 32;
        ushort* dst = Vt + (size_t)((b * NH_ + h) * 64 + d) * N_ + (bm & (N_ - 1)) + m0;
        float vsum = 0.f;
#pragma unroll
        for (int jj = 0; jj < 4; ++jj) {
            uint4 tt = *(const uint4*)&T[rid * 136 + m0 + jj * 8];
            *(uint4*)(dst + jj * 8) = tt;
            uint uu[4] = {tt.x, tt.y, tt.z, tt.w};
#pragma unroll
            for (int q2 = 0; q2 < 4; ++q2) {
                vsum += __uint_as_float(uu[q2] << 16);
                vsum += __uint_as_float(uu[q2] & 0xffff0000u);
            }
        }
        vsum += __shfl_xor(vsum, 1);
        vsum += __shfl_xor(vsum, 2);
        if (quad == 0) VmP[(bm >> 7) * 1024 + n_c] = vsum;   // race-free slot
    }
}

// ---------------------------------------------------------------------------
// Flash-MFMA attention, no-max softmax (Q pre-scaled by SC2). WG = 256 thr
// (4 waves) x 128 queries; each wave owns 2 q-tiles so every K/V fragment
// ds_read feeds 2 MFMAs. Query-block index through folded permutation
// (tb<8 ? tb : 23-tb) for load balance. cnt computed in-kernel (binary
// search, hidden under Q staging). Prefix visibility => ceil(cnt[last]/64)
// KV tiles. cnt==0 queries -> sum of VmP partials / 1024 (reference's
// finfo.min uniform softmax).
// ---------------------------------------------------------------------------
__global__ __launch_bounds__(256) void attn_mfma(const ushort* __restrict__ Qp,
                                                 const ushort* __restrict__ Kp,
                                                 const ushort* __restrict__ VtG,
                                                 const int* __restrict__ ends,
                                                 const float* __restrict__ VmP,
                                                 ushort* __restrict__ AO)
{
    __shared__ __align__(16) ushort Qs[128 * 64];
    __shared__ __align__(16) ushort Ks[64 * 64];
    __shared__ __align__(16) ushort Vs[64 * 64];
    __shared__ __align__(16) ushort Ps[128][72];
    __shared__ int cntS[128];

    const int id = blockIdx.x;
    const int b = id & 1, h = (id >> 1) & 15;
    const int tb = id >> 5;
    const int t0 = (tb < 8 ? tb : 23 - tb) << 7;   // folded permutation
    const int tid = threadIdx.x, lane = tid & 63, w = tid >> 6;
    const int c = lane & 15, g = lane >> 4;

    // stage Q tile (128 q x 64 d), swizzled: 1024 units, 4 per lane
#pragma unroll
    for (int jj = 0; jj < 4; ++jj) {
        int u = w * 256 + jj * 64 + lane;
        int row = u >> 3, gs = (u & 7) ^ (row & 7);
        gload16(Qs + (w * 256 + jj * 64) * 8,
                Qp + (size_t)(b * S_ + t0 + row) * H_ + h * 64 + gs * 8);
    }
    // visibility counts for this WG's 128 queries (hidden under Q staging)
    if (tid < 128) {
        int t = t0 + tid;
        int lo = 0, hi = N_;
        while (lo < hi) { int mid = (lo + hi) >> 1; if (ends[mid] <= t) lo = mid + 1; else hi = mid; }
        cntS[tid] = lo;
    }

    // K/V staging addresses (loop-invariant parts)
    const int u0 = (w * 2) * 64 + lane, row0 = u0 >> 3, gs0 = (u0 & 7) ^ (row0 & 7);
    const int u1 = (w * 2 + 1) * 64 + lane, row1 = u1 >> 3, gs1 = (u1 & 7) ^ (row1 & 7);
    const ushort* kp0 = Kp + (size_t)(b * N_ + row0) * H_ + h * 64 + gs0 * 8;
    const ushort* kp1 = Kp + (size_t)(b * N_ + row1) * H_ + h * 64 + gs1 * 8;
    const ushort* vp0 = VtG + (size_t)((b * NH_ + h) * 64 + row0) * N_ + gs0 * 8;
    const ushort* vp1 = VtG + (size_t)((b * NH_ + h) * 64 + row1) * N_ + gs1 * 8;

    float l0 = 0.f, l1 = 0.f;
    f32x4 o0[4] = {}, o1[4] = {};

    __syncthreads();
    const int cntv0 = cntS[w * 32 + c];
    const int cntv1 = cntS[w * 32 + 16 + c];
    const int cnt_min = cntS[0];
    const int ntmax = (cntS[127] + 63) >> 6;

    // Q fragments (loop-invariant): 2 q-tiles per wave
    bf16x8 bq0[2], bq1[2];
#pragma unroll
    for (int ks = 0; ks < 2; ++ks) {
        int s = ks * 4 + g;
        int ra = w * 32 + c;
        bq0[ks] = *(const bf16x8*)(Qs + (ra * 8 + (s ^ (ra & 7))) * 8);
        int rb = w * 32 + 16 + c;
        bq1[ks] = *(const bf16x8*)(Qs + (rb * 8 + (s ^ (rb & 7))) * 8);
    }

    for (int nt = 0; nt < ntmax; ++nt) {
        gload16(Ks + (w * 2) * 512, kp0 + (size_t)nt * 64 * H_);
        gload16(Ks + (w * 2 + 1) * 512, kp1 + (size_t)nt * 64 * H_);
        gload16(Vs + (w * 2) * 512, vp0 + nt * 64);
        gload16(Vs + (w * 2 + 1) * 512, vp1 + nt * 64);
        __syncthreads();

        // S^T = K · Q^T for both q-tiles; each ak fragment feeds 2 MFMAs
        f32x4 st0[4] = {}, st1[4] = {};
#pragma unroll
        for (int ntile = 0; ntile < 4; ++ntile)
#pragma unroll
            for (int ks = 0; ks < 2; ++ks) {
                int row = ntile * 16 + c;
                int s = ks * 4 + g;
                bf16x8 ak = *(const bf16x8*)(Ks + (row * 8 + (s ^ (row & 7))) * 8);
                st0[ntile] = __builtin_amdgcn_mfma_f32_16x16x32_bf16(ak, bq0[ks], st0[ntile], 0, 0, 0);
                st1[ntile] = __builtin_amdgcn_mfma_f32_16x16x32_bf16(ak, bq1[ks], st1[ntile], 0, 0, 0);
            }

        // no-max softmax: p = exp2(st) (0 if masked)
        const bool full = ((nt + 1) << 6) <= cnt_min;   // wave-uniform
        float lsum0 = 0.f, lsum1 = 0.f;
        if (full) {
#pragma unroll
            for (int ntile = 0; ntile < 4; ++ntile) {
                float a0 = fexp2(st0[ntile][0]), a1 = fexp2(st0[ntile][1]);
                float a2 = fexp2(st0[ntile][2]), a3 = fexp2(st0[ntile][3]);
                lsum0 += (a0 + a1) + (a2 + a3);
                uint2 pw; pw.x = pk2(a0, a1); pw.y = pk2(a2, a3);
                *(uint2*)&Ps[w * 32 + c][ntile * 16 + g * 4] = pw;
                float b0 = fexp2(st1[ntile][0]), b1 = fexp2(st1[ntile][1]);
                float b2 = fexp2(st1[ntile][2]), b3 = fexp2(st1[ntile][3]);
                lsum1 += (b0 + b1) + (b2 + b3);
                uint2 qw; qw.x = pk2(b0, b1); qw.y = pk2(b2, b3);
                *(uint2*)&Ps[w * 32 + 16 + c][ntile * 16 + g * 4] = qw;
            }
        } else {
            const int base0 = (nt << 6) + g * 4 - cntv0;
            const int base1 = (nt << 6) + g * 4 - cntv1;
#pragma unroll
            for (int ntile = 0; ntile < 4; ++ntile) {
                float a0 = (base0 + ntile * 16 + 0 >= 0) ? 0.f : fexp2(st0[ntile][0]);
                float a1 = (base0 + ntile * 16 + 1 >= 0) ? 0.f : fexp2(st0[ntile][1]);
                float a2 = (base0 + ntile * 16 + 2 >= 0) ? 0.f : fexp2(st0[ntile][2]);
                float a3 = (base0 + ntile * 16 + 3 >= 0) ? 0.f : fexp2(st0[ntile][3]);
                lsum0 += (a0 + a1) + (a2 + a3);
                uint2 pw; pw.x = pk2(a0, a1); pw.y = pk2(a2, a3);
                *(uint2*)&Ps[w * 32 + c][ntile * 16 + g * 4] = pw;
                float b0 = (base1 + ntile * 16 + 0 >= 0) ? 0.f : fexp2(st1[ntile][0]);
                float b1 = (base1 + ntile * 16 + 1 >= 0) ? 0.f : fexp2(st1[ntile][1]);
                float b2 = (base1 + ntile * 16 + 2 >= 0) ? 0.f : fexp2(st1[ntile][2]);
                float b3 = (base1 + ntile * 16 + 3 >= 0) ? 0.f : fexp2(st1[ntile][3]);
                lsum1 += (b0 + b1) + (b2 + b3);
                uint2 qw; qw.x = pk2(b0, b1); qw.y = pk2(b2, b3);
                *(uint2*)&Ps[w * 32 + 16 + c][ntile * 16 + g * 4] = qw;
            }
        }
        lsum0 += __shfl_xor(lsum0, 16); lsum0 += __shfl_xor(lsum0, 32);
        lsum1 += __shfl_xor(lsum1, 16); lsum1 += __shfl_xor(lsum1, 32);
        l0 += lsum0; l1 += lsum1;

        // O += P · V; each bv fragment feeds 2 MFMAs
        bf16x8 ap0[2], ap1[2];
#pragma unroll
        for (int ks = 0; ks < 2; ++ks) {
            ap0[ks] = *(const bf16x8*)&Ps[w * 32 + c][ks * 32 + g * 8];
            ap1[ks] = *(const bf16x8*)&Ps[w * 32 + 16 + c][ks * 32 + g * 8];
        }
#pragma unroll
        for (int dt = 0; dt < 4; ++dt)
#pragma unroll
            for (int ks = 0; ks < 2; ++ks) {
                int row = dt * 16 + c;
                int s = ks * 4 + g;
                bf16x8 bv = *(const bf16x8*)(Vs + (row * 8 + (s ^ (row & 7))) * 8);
                o0[dt] = __builtin_amdgcn_mfma_f32_16x16x32_bf16(ap0[ks], bv, o0[dt], 0, 0, 0);
                o1[dt] = __builtin_amdgcn_mfma_f32_16x16x32_bf16(ap1[ks], bv, o1[dt], 0, 0, 0);
            }
        __syncthreads();
    }

    // epilogue (both q-tiles)
#pragma unroll
    for (int qt = 0; qt < 2; ++qt) {
        float invl = 1.f / (qt == 0 ? l0 : l1);
        f32x4* o = (qt == 0 ? o0 : o1);
        float lr[4]; int cq[4];
#pragma unroll
        for (int r = 0; r < 4; ++r) {
            lr[r] = __shfl(invl, g * 4 + r);
            cq[r] = cntS[w * 32 + qt * 16 + g * 4 + r];
        }
#pragma unroll
        for (int dt = 0; dt < 4; ++dt)
#pragma unroll
            for (int r = 0; r < 4; ++r) {
                int q = t0 + w * 32 + qt * 16 + g * 4 + r;
                float val = o[dt][r] * lr[r];
                if (cq[r] == 0) {
                    float sm = 0.f;
#pragma unroll
                    for (int j = 0; j < 8; ++j)
                        sm += VmP[(b * 8 + j) * 1024 + h * 64 + dt * 16 + c];
                    val = sm * (1.f / 1024.f);
                }
                AO[(size_t)(b * S_ + q) * H_ + h * 64 + dt * 16 + c] = f2bf(val);
            }
    }
}

// ---------------------------------------------------------------------------
extern "C" void kernel_launch(void* const* d_in, const int* in_sizes, int n_in,
                              void* d_out, int out_size, void* d_ws, size_t ws_size,
                              hipStream_t stream) {
    const float* token_q    = (const float*)d_in[0];
    const float* block_kv   = (const float*)d_in[1];
    const int*   block_ends = (const int*)d_in[2];
    const float* Wq = (const float*)d_in[3];
    const float* Wk = (const float*)d_in[4];
    const float* Wv = (const float*)d_in[5];
    const float* Wo = (const float*)d_in[6];
    float* out = (float*)d_out;

    // ws layout (ushort units): Qp 0..4M (AO aliases Qp: per-WG
    // read-before-write) | Kp 4..6M | VtG 6..8M | VmP 8M.. (16384 floats)
    ushort* ws  = (ushort*)d_ws;
    ushort* Qp  = ws;
    ushort* Kp  = ws + (size_t)4 * 1024 * 1024;
    ushort* VtG = ws + (size_t)6 * 1024 * 1024;
    float*  VmP = (float*)(ws + (size_t)8 * 1024 * 1024);

    // fused Q + K + V projections (fp32 sources, inline convert; V also
    // writes VmP partial column sums)
    gemm_all<<<512, 512, 0, stream>>>(0, token_q, block_kv, Wq, Wk, Wv, Wo,
                                      Qp, Kp, VtG, nullptr, nullptr, VmP);
    // attention -> AO (aliases Qp); computes its own visibility counts
    attn_mfma<<<512, 256, 0, stream>>>(Qp, Kp, VtG, block_ends, VmP, Qp);
    // output projection -> fp32 out (Wo converted inline)
    gemm_all<<<256, 512, 0, stream>>>(1, token_q, block_kv, Wq, Wk, Wv, Wo,
                                      Qp, Kp, VtG, Qp, out, VmP);
}

// Round 7
// 159.079 us; speedup vs baseline: 1.2923x; 1.2923x over previous
//
#include <hip/hip_runtime.h>
#include <float.h>
#include <stdint.h>

#define B_  2
#define S_  2048
#define N_  1024
#define H_  1024
#define NH_ 16
#define K_  1024

typedef __attribute__((ext_vector_type(8))) short bf16x8;
typedef __attribute__((ext_vector_type(4))) float f32x4;

typedef __attribute__((address_space(3))) uint32_t lds_u32;
typedef __attribute__((address_space(1))) uint32_t glb_u32;

// async global->LDS, 16B per lane; LDS dest = wave-uniform base + lane*16
__device__ __forceinline__ void gload16(void* l, const void* g) {
    __builtin_amdgcn_global_load_lds((const glb_u32*)g, (lds_u32*)l, 16, 0, 0);
}

// round-to-nearest-even fp32 -> bf16 bits
__device__ __forceinline__ ushort f2bf(float f) {
    uint32_t u = __float_as_uint(f);
    u = (u + 0x7fffu + ((u >> 16) & 1u)) >> 16;
    return (ushort)u;
}

#if __has_builtin(__builtin_amdgcn_cvt_pk_bf16_f32)
typedef __attribute__((ext_vector_type(2))) __bf16 bfp2;
__device__ __forceinline__ uint pk2(float a, float b) {
    bfp2 v = __builtin_amdgcn_cvt_pk_bf16_f32(a, b);
    return __builtin_bit_cast(uint, v);
}
#else
__device__ __forceinline__ uint pk2(float a, float b) {
    return (uint)f2bf(a) | ((uint)f2bf(b) << 16);
}
#endif

__device__ __forceinline__ float fexp2(float x) {
#if __has_builtin(__builtin_amdgcn_exp2f)
    return __builtin_amdgcn_exp2f(x);
#else
    return exp2f(x);
#endif
}

#define SC2 0.180336880f   /* (1/sqrt(64)) * log2(e) — folded into Q proj */

// ---------------------------------------------------------------------------
// Prep: fp32 -> bf16 converts. CRITICAL side effect: the bf16 writes leave all
// GEMM operands L2/L3-hot (R6 showed staging from cold fp32 costs 105 MB of
// HBM refetch in the GEMM itself — 2x slower).
// ws layout (ushort): qx 0..4M | kvx 4..6M | wq 6M | wk 7M | wv 8M | wo 9M
// ---------------------------------------------------------------------------
__global__ __launch_bounds__(256) void prep_kernel(const float* __restrict__ tq,
        const float* __restrict__ kv, const float* __restrict__ wq,
        const float* __restrict__ wk, const float* __restrict__ wv,
        const float* __restrict__ wo, ushort* __restrict__ dst)
{
    int blk = blockIdx.x;
    const float* src; size_t base;
    if (blk < 2048)      { src = tq; base = 0;       }
    else if (blk < 3072) { src = kv; base = 4194304; blk -= 2048; }
    else if (blk < 3584) { src = wq; base = 6291456; blk -= 3072; }
    else if (blk < 4096) { src = wk; base = 7340032; blk -= 3584; }
    else if (blk < 4608) { src = wv; base = 8388608; blk -= 4096; }
    else                 { src = wo; base = 9437184; blk -= 4608; }
    size_t i = (size_t)blk * 2048 + threadIdx.x * 8;
    float4 a = *(const float4*)(src + i);
    float4 b = *(const float4*)(src + i + 4);
    uint4 o;
    o.x = pk2(a.x, a.y); o.y = pk2(a.z, a.w);
    o.z = pk2(b.x, b.y); o.w = pk2(b.z, b.w);
    *(uint4*)(dst + base + i) = o;
}

// ---------------------------------------------------------------------------
// QKV projections: 128x128-tile bf16 MFMA GEMM (512 thr = 8 waves, BK=64,
// XOR-swizzled LDS via global_load_lds w=16).
// idx<256 -> Qp = qx@Wq^T * SC2 (bf16); idx<384 -> Kp = kvx@Wk^T (bf16);
// else -> VtG = transpose-per-head(kvx@Wv^T) + VmP race-free partial column
// sums (one slot per (m-tile, col); summed by attn for cnt==0 queries).
// ---------------------------------------------------------------------------
__global__ __launch_bounds__(512) void gemm_qkv(
        const ushort* __restrict__ qx, const ushort* __restrict__ kvx,
        const ushort* __restrict__ wq, const ushort* __restrict__ wk,
        const ushort* __restrict__ wv,
        ushort* __restrict__ Qp, ushort* __restrict__ Kp,
        ushort* __restrict__ VtG, float* __restrict__ VmP)
{
    __shared__ __align__(16) ushort smem[17408];   // Xs | Ws ; reused as T in kind-2
    ushort* Xs = smem;
    ushort* Ws = smem + 8192;

    const ushort* X; const ushort* W; void* Yp; int kind; float scale = 1.f;
    int bm, bn;
    {
        int idx = blockIdx.x;
        if (idx < 256)      { X = qx;  W = wq; Yp = Qp;  kind = 0; scale = SC2;
                              bm = (idx >> 3) * 128; bn = (idx & 7) * 128; }
        else if (idx < 384) { int j = idx - 256; X = kvx; W = wk; Yp = Kp; kind = 0;
                              bm = (j >> 3) * 128; bn = (j & 7) * 128; }
        else                { int j = idx - 384; X = kvx; W = wv; Yp = VtG; kind = 2;
                              bm = (j >> 3) * 128; bn = (j & 7) * 128; }
    }

    const int tid = threadIdx.x;
    const int lane = tid & 63, w = tid >> 6;
    const int wy = w >> 1, wx = w & 1;
    const int c = lane & 15, g = lane >> 4;

    f32x4 acc[2][4] = {};

    for (int kt = 0; kt < 16; ++kt) {
        const int k0 = kt * 64;
#pragma unroll
        for (int j = 0; j < 2; ++j) {
            int u = w * 128 + j * 64 + lane;
            int row = u >> 3, gs = (u & 7) ^ (row & 7);
            gload16(Xs + (w * 128 + j * 64) * 8, X + (size_t)(bm + row) * K_ + k0 + gs * 8);
            gload16(Ws + (w * 128 + j * 64) * 8, W + (size_t)(bn + row) * K_ + k0 + gs * 8);
        }
        __syncthreads();
#pragma unroll
        for (int ks = 0; ks < 2; ++ks) {
            bf16x8 af[2], bfr[4];
#pragma unroll
            for (int mi = 0; mi < 2; ++mi) {
                int row = wy * 32 + mi * 16 + c;
                int s = ks * 4 + g;
                af[mi] = *(const bf16x8*)(Xs + (row * 8 + (s ^ (row & 7))) * 8);
            }
#pragma unroll
            for (int ni = 0; ni < 4; ++ni) {
                int row = wx * 64 + ni * 16 + c;
                int s = ks * 4 + g;
                bfr[ni] = *(const bf16x8*)(Ws + (row * 8 + (s ^ (row & 7))) * 8);
            }
#pragma unroll
            for (int mi = 0; mi < 2; ++mi)
#pragma unroll
                for (int ni = 0; ni < 4; ++ni)
                    acc[mi][ni] = __builtin_amdgcn_mfma_f32_16x16x32_bf16(af[mi], bfr[ni], acc[mi][ni], 0, 0, 0);
        }
        __syncthreads();
    }

    if (kind == 0) {
        ushort* Y = (ushort*)Yp;
#pragma unroll
        for (int mi = 0; mi < 2; ++mi)
#pragma unroll
            for (int ni = 0; ni < 4; ++ni)
#pragma unroll
                for (int r = 0; r < 4; ++r) {
                    int row = bm + wy * 32 + mi * 16 + g * 4 + r;
                    int col = bn + wx * 64 + ni * 16 + c;
                    Y[(size_t)row * 1024 + col] = f2bf(acc[mi][ni][r] * scale);
                }
    } else {
        // V transposed per head + VmP partial column sums
        ushort* T = smem;                       // [128][136]
#pragma unroll
        for (int mi = 0; mi < 2; ++mi)
#pragma unroll
            for (int ni = 0; ni < 4; ++ni) {
                ushort4 v4;
                v4.x = f2bf(acc[mi][ni][0]); v4.y = f2bf(acc[mi][ni][1]);
                v4.z = f2bf(acc[mi][ni][2]); v4.w = f2bf(acc[mi][ni][3]);
                *(ushort4*)&T[(wx * 64 + ni * 16 + c) * 136 + wy * 32 + mi * 16 + g * 4] = v4;
            }
        __syncthreads();
        ushort* Vt = (ushort*)Yp;
        int b = bm >> 10;
        int rid = tid >> 2, quad = tid & 3;
        int n_c = bn + rid;                     // col (h*64+d) in [0,1024)
        int h = n_c >> 6, d = n_c & 63;
        int m0 = quad * 32;
        ushort* dst = Vt + (size_t)((b * NH_ + h) * 64 + d) * N_ + (bm & (N_ - 1)) + m0;
        float vsum = 0.f;
#pragma unroll
        for (int jj = 0; jj < 4; ++jj) {
            uint4 tt = *(const uint4*)&T[rid * 136 + m0 + jj * 8];
            *(uint4*)(dst + jj * 8) = tt;
            uint uu[4] = {tt.x, tt.y, tt.z, tt.w};
#pragma unroll
            for (int q2 = 0; q2 < 4; ++q2) {
                vsum += __uint_as_float(uu[q2] << 16);
                vsum += __uint_as_float(uu[q2] & 0xffff0000u);
            }
        }
        vsum += __shfl_xor(vsum, 1);
        vsum += __shfl_xor(vsum, 2);
        if (quad == 0) VmP[(bm >> 7) * 1024 + n_c] = vsum;   // race-free slot
    }
}

// ---------------------------------------------------------------------------
// Flash-MFMA attention, no-max softmax (Q pre-scaled by SC2). WG = 256 thr
// (4 waves) x 128 queries; each wave owns 2 q-tiles so every K/V fragment
// ds_read feeds 2 MFMAs. Folded permutation (tb<8 ? tb : 23-tb) balances
// per-CU tile counts. cnt computed in-kernel (hidden under Q staging).
// Prefix visibility => ceil(cnt[last]/64) KV tiles. cnt==0 queries -> sum of
// VmP partials / 1024 (reference's finfo.min uniform softmax).
// ---------------------------------------------------------------------------
__global__ __launch_bounds__(256) void attn_mfma(const ushort* __restrict__ Qp,
                                                 const ushort* __restrict__ Kp,
                                                 const ushort* __restrict__ VtG,
                                                 const int* __restrict__ ends,
                                                 const float* __restrict__ VmP,
                                                 ushort* __restrict__ AO)
{
    __shared__ __align__(16) ushort Qs[128 * 64];
    __shared__ __align__(16) ushort Ks[64 * 64];
    __shared__ __align__(16) ushort Vs[64 * 64];
    __shared__ __align__(16) ushort Ps[128][72];
    __shared__ int cntS[128];

    const int id = blockIdx.x;
    const int b = id & 1, h = (id >> 1) & 15;
    const int tb = id >> 5;
    const int t0 = (tb < 8 ? tb : 23 - tb) << 7;   // folded permutation
    const int tid = threadIdx.x, lane = tid & 63, w = tid >> 6;
    const int c = lane & 15, g = lane >> 4;

    // stage Q tile (128 q x 64 d), swizzled: 1024 units, 4 per lane
#pragma unroll
    for (int jj = 0; jj < 4; ++jj) {
        int u = w * 256 + jj * 64 + lane;
        int row = u >> 3, gs = (u & 7) ^ (row & 7);
        gload16(Qs + (w * 256 + jj * 64) * 8,
                Qp + (size_t)(b * S_ + t0 + row) * H_ + h * 64 + gs * 8);
    }
    // visibility counts for this WG's 128 queries (hidden under Q staging)
    if (tid < 128) {
        int t = t0 + tid;
        int lo = 0, hi = N_;
        while (lo < hi) { int mid = (lo + hi) >> 1; if (ends[mid] <= t) lo = mid + 1; else hi = mid; }
        cntS[tid] = lo;
    }

    // K/V staging addresses (loop-invariant parts)
    const int u0 = (w * 2) * 64 + lane, row0 = u0 >> 3, gs0 = (u0 & 7) ^ (row0 & 7);
    const int u1 = (w * 2 + 1) * 64 + lane, row1 = u1 >> 3, gs1 = (u1 & 7) ^ (row1 & 7);
    const ushort* kp0 = Kp + (size_t)(b * N_ + row0) * H_ + h * 64 + gs0 * 8;
    const ushort* kp1 = Kp + (size_t)(b * N_ + row1) * H_ + h * 64 + gs1 * 8;
    const ushort* vp0 = VtG + (size_t)((b * NH_ + h) * 64 + row0) * N_ + gs0 * 8;
    const ushort* vp1 = VtG + (size_t)((b * NH_ + h) * 64 + row1) * N_ + gs1 * 8;

    float l0 = 0.f, l1 = 0.f;
    f32x4 o0[4] = {}, o1[4] = {};

    __syncthreads();
    const int cntv0 = cntS[w * 32 + c];
    const int cntv1 = cntS[w * 32 + 16 + c];
    const int cnt_min = cntS[0];
    const int ntmax = (cntS[127] + 63) >> 6;

    // Q fragments (loop-invariant): 2 q-tiles per wave
    bf16x8 bq0[2], bq1[2];
#pragma unroll
    for (int ks = 0; ks < 2; ++ks) {
        int s = ks * 4 + g;
        int ra = w * 32 + c;
        bq0[ks] = *(const bf16x8*)(Qs + (ra * 8 + (s ^ (ra & 7))) * 8);
        int rb = w * 32 + 16 + c;
        bq1[ks] = *(const bf16x8*)(Qs + (rb * 8 + (s ^ (rb & 7))) * 8);
    }

    for (int nt = 0; nt < ntmax; ++nt) {
        gload16(Ks + (w * 2) * 512, kp0 + (size_t)nt * 64 * H_);
        gload16(Ks + (w * 2 + 1) * 512, kp1 + (size_t)nt * 64 * H_);
        gload16(Vs + (w * 2) * 512, vp0 + nt * 64);
        gload16(Vs + (w * 2 + 1) * 512, vp1 + nt * 64);
        __syncthreads();

        // S^T = K · Q^T for both q-tiles; each ak fragment feeds 2 MFMAs
        f32x4 st0[4] = {}, st1[4] = {};
#pragma unroll
        for (int ntile = 0; ntile < 4; ++ntile)
#pragma unroll
            for (int ks = 0; ks < 2; ++ks) {
                int row = ntile * 16 + c;
                int s = ks * 4 + g;
                bf16x8 ak = *(const bf16x8*)(Ks + (row * 8 + (s ^ (row & 7))) * 8);
                st0[ntile] = __builtin_amdgcn_mfma_f32_16x16x32_bf16(ak, bq0[ks], st0[ntile], 0, 0, 0);
                st1[ntile] = __builtin_amdgcn_mfma_f32_16x16x32_bf16(ak, bq1[ks], st1[ntile], 0, 0, 0);
            }

        // no-max softmax: p = exp2(st) (0 if masked)
        const bool full = ((nt + 1) << 6) <= cnt_min;   // wave-uniform
        float lsum0 = 0.f, lsum1 = 0.f;
        if (full) {
#pragma unroll
            for (int ntile = 0; ntile < 4; ++ntile) {
                float a0 = fexp2(st0[ntile][0]), a1 = fexp2(st0[ntile][1]);
                float a2 = fexp2(st0[ntile][2]), a3 = fexp2(st0[ntile][3]);
                lsum0 += (a0 + a1) + (a2 + a3);
                uint2 pw; pw.x = pk2(a0, a1); pw.y = pk2(a2, a3);
                *(uint2*)&Ps[w * 32 + c][ntile * 16 + g * 4] = pw;
                float b0 = fexp2(st1[ntile][0]), b1 = fexp2(st1[ntile][1]);
                float b2 = fexp2(st1[ntile][2]), b3 = fexp2(st1[ntile][3]);
                lsum1 += (b0 + b1) + (b2 + b3);
                uint2 qw; qw.x = pk2(b0, b1); qw.y = pk2(b2, b3);
                *(uint2*)&Ps[w * 32 + 16 + c][ntile * 16 + g * 4] = qw;
            }
        } else {
            const int base0 = (nt << 6) + g * 4 - cntv0;
            const int base1 = (nt << 6) + g * 4 - cntv1;
#pragma unroll
            for (int ntile = 0; ntile < 4; ++ntile) {
                float a0 = (base0 + ntile * 16 + 0 >= 0) ? 0.f : fexp2(st0[ntile][0]);
                float a1 = (base0 + ntile * 16 + 1 >= 0) ? 0.f : fexp2(st0[ntile][1]);
                float a2 = (base0 + ntile * 16 + 2 >= 0) ? 0.f : fexp2(st0[ntile][2]);
                float a3 = (base0 + ntile * 16 + 3 >= 0) ? 0.f : fexp2(st0[ntile][3]);
                lsum0 += (a0 + a1) + (a2 + a3);
                uint2 pw; pw.x = pk2(a0, a1); pw.y = pk2(a2, a3);
                *(uint2*)&Ps[w * 32 + c][ntile * 16 + g * 4] = pw;
                float b0 = (base1 + ntile * 16 + 0 >= 0) ? 0.f : fexp2(st1[ntile][0]);
                float b1 = (base1 + ntile * 16 + 1 >= 0) ? 0.f : fexp2(st1[ntile][1]);
                float b2 = (base1 + ntile * 16 + 2 >= 0) ? 0.f : fexp2(st1[ntile][2]);
                float b3 = (base1 + ntile * 16 + 3 >= 0) ? 0.f : fexp2(st1[ntile][3]);
                lsum1 += (b0 + b1) + (b2 + b3);
                uint2 qw; qw.x = pk2(b0, b1); qw.y = pk2(b2, b3);
                *(uint2*)&Ps[w * 32 + 16 + c][ntile * 16 + g * 4] = qw;
            }
        }
        lsum0 += __shfl_xor(lsum0, 16); lsum0 += __shfl_xor(lsum0, 32);
        lsum1 += __shfl_xor(lsum1, 16); lsum1 += __shfl_xor(lsum1, 32);
        l0 += lsum0; l1 += lsum1;

        // O += P · V; each bv fragment feeds 2 MFMAs
        bf16x8 ap0[2], ap1[2];
#pragma unroll
        for (int ks = 0; ks < 2; ++ks) {
            ap0[ks] = *(const bf16x8*)&Ps[w * 32 + c][ks * 32 + g * 8];
            ap1[ks] = *(const bf16x8*)&Ps[w * 32 + 16 + c][ks * 32 + g * 8];
        }
#pragma unroll
        for (int dt = 0; dt < 4; ++dt)
#pragma unroll
            for (int ks = 0; ks < 2; ++ks) {
                int row = dt * 16 + c;
                int s = ks * 4 + g;
                bf16x8 bv = *(const bf16x8*)(Vs + (row * 8 + (s ^ (row & 7))) * 8);
                o0[dt] = __builtin_amdgcn_mfma_f32_16x16x32_bf16(ap0[ks], bv, o0[dt], 0, 0, 0);
                o1[dt] = __builtin_amdgcn_mfma_f32_16x16x32_bf16(ap1[ks], bv, o1[dt], 0, 0, 0);
            }
        __syncthreads();
    }

    // epilogue (both q-tiles)
#pragma unroll
    for (int qt = 0; qt < 2; ++qt) {
        float invl = 1.f / (qt == 0 ? l0 : l1);
        f32x4* o = (qt == 0 ? o0 : o1);
        float lr[4]; int cq[4];
#pragma unroll
        for (int r = 0; r < 4; ++r) {
            lr[r] = __shfl(invl, g * 4 + r);
            cq[r] = cntS[w * 32 + qt * 16 + g * 4 + r];
        }
#pragma unroll
        for (int dt = 0; dt < 4; ++dt)
#pragma unroll
            for (int r = 0; r < 4; ++r) {
                int q = t0 + w * 32 + qt * 16 + g * 4 + r;
                float val = o[dt][r] * lr[r];
                if (cq[r] == 0) {
                    float sm = 0.f;
#pragma unroll
                    for (int j = 0; j < 8; ++j)
                        sm += VmP[(b * 8 + j) * 1024 + h * 64 + dt * 16 + c];
                    val = sm * (1.f / 1024.f);
                }
                AO[(size_t)(b * S_ + q) * H_ + h * 64 + dt * 16 + c] = f2bf(val);
            }
    }
}

// ---------------------------------------------------------------------------
// Output projection: out = AO[4096,1024] @ Wo^T, fp32 out. 64(M)x128(N)
// tiles -> 512 WGs = 2/CU (vs 256 = 1/CU before: doubles waves available to
// hide staging/barrier drains at the pipeline tail). 512 thr = 8 waves in a
// 2(M)x4(N) wave grid, each wave 32x32 C (2x2 16x16 frags).
// ---------------------------------------------------------------------------
__global__ __launch_bounds__(512) void gemm_out(const ushort* __restrict__ AO,
                                                const ushort* __restrict__ wo,
                                                float* __restrict__ out)
{
    __shared__ __align__(16) ushort Xs[64 * 64];    // 4096 ushorts
    __shared__ __align__(16) ushort Ws[128 * 64];   // 8192 ushorts

    const int bm = (blockIdx.x >> 3) * 64;
    const int bn = (blockIdx.x & 7) * 128;
    const int tid = threadIdx.x, lane = tid & 63, w = tid >> 6;
    const int wy = w >> 2, wx = w & 3;
    const int c = lane & 15, g = lane >> 4;

    // staging map: X 512 units (1/lane), W 1024 units (2/lane)
    const int rx = tid >> 3,          sx = (tid & 7) ^ (rx & 7);
    const int rw0 = tid >> 3,         sw0 = (tid & 7) ^ (rw0 & 7);
    const int uw1 = tid + 512;
    const int rw1 = uw1 >> 3,         sw1 = (uw1 & 7) ^ (rw1 & 7);

    const ushort* xp  = AO + (size_t)(bm + rx) * K_ + sx * 8;
    const ushort* wp0 = wo + (size_t)(bn + rw0) * K_ + sw0 * 8;
    const ushort* wp1 = wo + (size_t)(bn + rw1) * K_ + sw1 * 8;

    f32x4 acc[2][2] = {};

    for (int kt = 0; kt < 16; ++kt) {
        const int k0 = kt * 64;
        gload16(Xs + (w * 64) * 8, xp + k0);
        gload16(Ws + (w * 64) * 8, wp0 + k0);
        gload16(Ws + (512 + w * 64) * 8, wp1 + k0);
        __syncthreads();
#pragma unroll
        for (int ks = 0; ks < 2; ++ks) {
            bf16x8 af[2], bfr[2];
            int s = ks * 4 + g;
#pragma unroll
            for (int mi = 0; mi < 2; ++mi) {
                int row = wy * 32 + mi * 16 + c;
                af[mi] = *(const bf16x8*)(Xs + (row * 8 + (s ^ (row & 7))) * 8);
            }
#pragma unroll
            for (int ni = 0; ni < 2; ++ni) {
                int row = wx * 32 + ni * 16 + c;
                bfr[ni] = *(const bf16x8*)(Ws + (row * 8 + (s ^ (row & 7))) * 8);
            }
#pragma unroll
            for (int mi = 0; mi < 2; ++mi)
#pragma unroll
                for (int ni = 0; ni < 2; ++ni)
                    acc[mi][ni] = __builtin_amdgcn_mfma_f32_16x16x32_bf16(af[mi], bfr[ni], acc[mi][ni], 0, 0, 0);
        }
        __syncthreads();
    }

#pragma unroll
    for (int mi = 0; mi < 2; ++mi)
#pragma unroll
        for (int ni = 0; ni < 2; ++ni)
#pragma unroll
            for (int r = 0; r < 4; ++r) {
                int row = bm + wy * 32 + mi * 16 + g * 4 + r;
                int col = bn + wx * 32 + ni * 16 + c;
                out[(size_t)row * 1024 + col] = acc[mi][ni][r];
            }
}

// ---------------------------------------------------------------------------
extern "C" void kernel_launch(void* const* d_in, const int* in_sizes, int n_in,
                              void* d_out, int out_size, void* d_ws, size_t ws_size,
                              hipStream_t stream) {
    const float* token_q    = (const float*)d_in[0];
    const float* block_kv   = (const float*)d_in[1];
    const int*   block_ends = (const int*)d_in[2];
    const float* Wq = (const float*)d_in[3];
    const float* Wk = (const float*)d_in[4];
    const float* Wv = (const float*)d_in[5];
    const float* Wo = (const float*)d_in[6];
    float* out = (float*)d_out;

    // ws layout (ushort units):
    // qx 0..4M | kvx 4..6M | wq 6M | wk 7M | wv 8M | wo 9M | Qp 10..14M (AO
    // aliases Qp: per-WG read-before-write) | Kp 14..16M | VtG 16..18M | VmP
    ushort* ws  = (ushort*)d_ws;
    ushort* qx  = ws;
    ushort* kvx = ws + (size_t)4 * 1024 * 1024;
    ushort* wqb = ws + (size_t)6 * 1024 * 1024;
    ushort* wkb = ws + (size_t)7 * 1024 * 1024;
    ushort* wvb = ws + (size_t)8 * 1024 * 1024;
    ushort* wob = ws + (size_t)9 * 1024 * 1024;
    ushort* Qp  = ws + (size_t)10 * 1024 * 1024;
    ushort* Kp  = ws + (size_t)14 * 1024 * 1024;
    ushort* VtG = ws + (size_t)16 * 1024 * 1024;
    float*  VmP = (float*)(ws + (size_t)18 * 1024 * 1024);   // 16384 floats

    // converts (also warms L2/L3 for the GEMM tile re-reads)
    prep_kernel<<<5120, 256, 0, stream>>>(token_q, block_kv, Wq, Wk, Wv, Wo, ws);
    // fused Q + K + V projections (V also writes VmP partials)
    gemm_qkv<<<512, 512, 0, stream>>>(qx, kvx, wqb, wkb, wvb, Qp, Kp, VtG, VmP);
    // attention -> AO (aliases Qp); computes its own visibility counts
    attn_mfma<<<512, 256, 0, stream>>>(Qp, Kp, VtG, block_ends, VmP, Qp);
    // output projection -> fp32 out (512 WGs, 64x128 tiles)
    gemm_out<<<512, 512, 0, stream>>>(Qp, wob, out);
}